// Round 1
// baseline (463.736 us; speedup 1.0000x reference)
//
#include <hip/hip_runtime.h>

#define IN_DIM 128
#define TM 64

// ---------------------------------------------------------------------------
// Fused 2-layer MLP: H = tanh(X@W1 + b1) @ W2 + b2, all fp32 (no fp32 MFMA on
// CDNA4 -> vector ALU). Block: 64 rows x 128 cols, 256 threads, thread tile
// 8 rows x 4 cols (float4). Tanh intermediate kept in LDS (Ts), W tiles
// staged in chunks of BK=32. LDS = 8+16+32 = 56 KB -> 2 blocks/CU.
// ---------------------------------------------------------------------------
__global__ __launch_bounds__(256) void mlp_fused(
    const float* __restrict__ X, const float* __restrict__ W1,
    const float* __restrict__ b1, const float* __restrict__ W2,
    const float* __restrict__ b2, float* __restrict__ H, int nrows)
{
    __shared__ float As[TM][32];        // 8 KB
    __shared__ float Ws[32][IN_DIM];    // 16 KB
    __shared__ float Ts[TM][IN_DIM];    // 32 KB
    const int t   = threadIdx.x;
    const int tx  = t & 31;             // col quad index
    const int ty  = t >> 5;             // 0..7
    const int c0  = tx * 4;
    const int row0 = blockIdx.x * TM;

    float acc[8][4];
#pragma unroll
    for (int i = 0; i < 8; ++i)
        acc[i][0] = acc[i][1] = acc[i][2] = acc[i][3] = 0.f;

    // ---- phase 1: T = tanh(X @ W1 + b1) ----
    for (int kk = 0; kk < 4; ++kk) {
        __syncthreads();
        // stage As (64x32): 512 float4, 2 per thread
#pragma unroll
        for (int s = 0; s < 2; ++s) {
            int idx = t + s * 256;
            int r = idx >> 3, q = idx & 7;
            int gr = row0 + r; gr = gr < nrows ? gr : nrows - 1;
            *(float4*)&As[r][q * 4] =
                *(const float4*)&X[(size_t)gr * IN_DIM + kk * 32 + q * 4];
        }
        // stage Ws (32x128): 1024 float4, 4 per thread
#pragma unroll
        for (int s = 0; s < 4; ++s) {
            int idx = t + s * 256;
            int r = idx >> 5, q = idx & 31;
            *(float4*)&Ws[r][q * 4] =
                *(const float4*)&W1[(size_t)(kk * 32 + r) * IN_DIM + q * 4];
        }
        __syncthreads();
#pragma unroll
        for (int k = 0; k < 32; ++k) {
            float4 w = *(const float4*)&Ws[k][c0];
#pragma unroll
            for (int i = 0; i < 8; ++i) {
                float a = As[ty * 8 + i][k];   // broadcast: 2 addrs/wave
                acc[i][0] += a * w.x; acc[i][1] += a * w.y;
                acc[i][2] += a * w.z; acc[i][3] += a * w.w;
            }
        }
    }
    {
        float4 bb = *(const float4*)&b1[c0];
#pragma unroll
        for (int i = 0; i < 8; ++i) {
            int r = ty * 8 + i;
            Ts[r][c0 + 0] = tanhf(acc[i][0] + bb.x);
            Ts[r][c0 + 1] = tanhf(acc[i][1] + bb.y);
            Ts[r][c0 + 2] = tanhf(acc[i][2] + bb.z);
            Ts[r][c0 + 3] = tanhf(acc[i][3] + bb.w);
        }
    }

    // ---- phase 2: H = T @ W2 + b2 ----
    float acc2[8][4];
#pragma unroll
    for (int i = 0; i < 8; ++i)
        acc2[i][0] = acc2[i][1] = acc2[i][2] = acc2[i][3] = 0.f;

    for (int kk = 0; kk < 4; ++kk) {
        __syncthreads();   // also guards Ts write -> Ts read (kk==0)
#pragma unroll
        for (int s = 0; s < 4; ++s) {
            int idx = t + s * 256;
            int r = idx >> 5, q = idx & 31;
            *(float4*)&Ws[r][q * 4] =
                *(const float4*)&W2[(size_t)(kk * 32 + r) * IN_DIM + q * 4];
        }
        __syncthreads();
#pragma unroll
        for (int k = 0; k < 32; ++k) {
            float4 w = *(const float4*)&Ws[k][c0];
#pragma unroll
            for (int i = 0; i < 8; ++i) {
                float a = Ts[ty * 8 + i][kk * 32 + k];
                acc2[i][0] += a * w.x; acc2[i][1] += a * w.y;
                acc2[i][2] += a * w.z; acc2[i][3] += a * w.w;
            }
        }
    }
    {
        float4 bb = *(const float4*)&b2[c0];
#pragma unroll
        for (int i = 0; i < 8; ++i) {
            int r = row0 + ty * 8 + i;
            if (r < nrows) {
                float4 o = make_float4(acc2[i][0] + bb.x, acc2[i][1] + bb.y,
                                       acc2[i][2] + bb.z, acc2[i][3] + bb.w);
                *(float4*)&H[(size_t)r * IN_DIM + c0] = o;
            }
        }
    }
}

// ---------------------------------------------------------------------------
// Mark nodes that appear in node_idx (only these need aggregation).
// ---------------------------------------------------------------------------
__global__ void build_flag(const int* __restrict__ node_idx,
                           int* __restrict__ flag, int B)
{
    int i = blockIdx.x * blockDim.x + threadIdx.x;
    if (i < B) flag[node_idx[i]] = 1;
}

// ---------------------------------------------------------------------------
// Compact edges whose src is flagged and whose value != 0.
// value = (src==dst) ? mask[ind] : 1.0, mask = {1,1,0,0} -> selfw in {0,1}.
// Wave-ballot compaction: one counter atomic per wave. rowsum accumulated
// here (one fp32 atomic per kept edge). s,d < 65536 -> pack into one uint.
// ---------------------------------------------------------------------------
__global__ void edge_build(const int* __restrict__ edges,
                           const int* __restrict__ flag,
                           const int* __restrict__ indp,
                           float* __restrict__ rowsum,
                           unsigned int* __restrict__ elist,
                           int* __restrict__ counter, int E)
{
    int e = blockIdx.x * blockDim.x + threadIdx.x;
    bool active = false;
    int s = 0, d = 0;
    if (e < E) {
        s = edges[2 * e];
        d = edges[2 * e + 1];
        float selfw = (*indp < 2) ? 1.0f : 0.0f;
        float w = (s == d) ? selfw : 1.0f;
        active = (w != 0.0f) && (flag[s] != 0);
        if (active) atomicAdd(&rowsum[s], w);
    }
    unsigned long long mask = __ballot(active);
    if (mask == 0ull) return;
    int lane   = threadIdx.x & 63;
    int before = __popcll(mask & ((1ull << lane) - 1ull));
    int leader = __ffsll((unsigned long long)mask) - 1;
    int base = 0;
    if (lane == leader) base = atomicAdd(counter, __popcll(mask));
    base = __shfl(base, leader, 64);
    if (active) elist[base + before] = ((unsigned)s << 16) | (unsigned)d;
}

// ---------------------------------------------------------------------------
// One wave per compacted edge: acc[s] += h[d] (128 floats, 2/lane, fp32
// atomics). Gathers of h hit L2/L3 (h = 25.6 MB).
// ---------------------------------------------------------------------------
__global__ void aggregate(const unsigned int* __restrict__ elist,
                          const int* __restrict__ counter,
                          const float* __restrict__ H,
                          float* __restrict__ acc)
{
    int nE   = *counter;
    int lane = threadIdx.x & 63;
    int wid  = (int)((blockIdx.x * blockDim.x + threadIdx.x) >> 6);
    int nw   = (int)((gridDim.x * blockDim.x) >> 6);
    for (int e = wid; e < nE; e += nw) {
        unsigned int p = elist[e];
        int s = (int)(p >> 16), d = (int)(p & 0xFFFFu);
        float2 hv = *(const float2*)&H[(size_t)d * 128 + lane * 2];
        atomicAdd(&acc[(size_t)s * 128 + lane * 2 + 0], hv.x);
        atomicAdd(&acc[(size_t)s * 128 + lane * 2 + 1], hv.y);
    }
}

// ---------------------------------------------------------------------------
// out[b] = acc[node_idx[b]] / max(rowsum, ->1 if 0). One float4 per thread.
// ---------------------------------------------------------------------------
__global__ void gather_out(const int* __restrict__ node_idx,
                           const float* __restrict__ acc,
                           const float* __restrict__ rowsum,
                           float* __restrict__ out, int B)
{
    int i = blockIdx.x * blockDim.x + threadIdx.x;
    if (i >= B * 32) return;
    int b = i >> 5, q = i & 31;
    int v = node_idx[b];
    float rs = rowsum[v];
    float inv = (rs == 0.0f) ? 1.0f : 1.0f / rs;
    float4 a = ((const float4*)acc)[(size_t)v * 32 + q];
    ((float4*)out)[i] = make_float4(a.x * inv, a.y * inv, a.z * inv, a.w * inv);
}

extern "C" void kernel_launch(void* const* d_in, const int* in_sizes, int n_in,
                              void* d_out, int out_size, void* d_ws, size_t ws_size,
                              hipStream_t stream)
{
    const int*   edges    = (const int*)d_in[0];
    const int*   node_idx = (const int*)d_in[1];
    const float* X        = (const float*)d_in[2];
    const float* W1       = (const float*)d_in[3];
    const float* b1       = (const float*)d_in[4];
    const float* W2       = (const float*)d_in[5];
    const float* b2       = (const float*)d_in[6];
    const int*   indp     = (const int*)d_in[7];

    const int E = in_sizes[0] / 2;
    const int B = in_sizes[1];
    const int N = in_sizes[2] / IN_DIM;

    // workspace layout (all 16B aligned for N=50000):
    // [acc N*128 f32][rowsum N f32][flag N i32][counter 16B][H N*128 f32][elist E u32]
    char*  ws      = (char*)d_ws;
    float* acc     = (float*)ws;
    float* rowsum  = (float*)(ws + (size_t)N * 128 * 4);
    int*   flag    = (int*)  (ws + (size_t)N * 129 * 4);
    int*   counter = (int*)  (ws + (size_t)N * 130 * 4);
    float* H       = (float*)(ws + (size_t)N * 130 * 4 + 16);
    unsigned int* elist =
        (unsigned int*)(ws + (size_t)N * 130 * 4 + 16 + (size_t)N * 128 * 4);

    // zero acc + rowsum + flag + counter in one async memset (capture-safe)
    size_t zbytes = (size_t)N * 130 * 4 + 16;
    hipMemsetAsync(d_ws, 0, zbytes, stream);

    hipLaunchKernelGGL(build_flag, dim3((B + 255) / 256), dim3(256), 0, stream,
                       node_idx, flag, B);
    hipLaunchKernelGGL(mlp_fused, dim3((N + TM - 1) / TM), dim3(256), 0, stream,
                       X, W1, b1, W2, b2, H, N);
    hipLaunchKernelGGL(edge_build, dim3((E + 255) / 256), dim3(256), 0, stream,
                       edges, flag, indp, rowsum, elist, counter, E);
    hipLaunchKernelGGL(aggregate, dim3(2048), dim3(256), 0, stream,
                       elist, counter, H, acc);
    hipLaunchKernelGGL(gather_out, dim3((B * 32 + 255) / 256), dim3(256), 0,
                       stream, node_idx, acc, rowsum, (float*)d_out, B);
}

// Round 2
// 336.012 us; speedup vs baseline: 1.3801x; 1.3801x over previous
//
#include <hip/hip_runtime.h>

#define IN_DIM 128
#define TM 64
#define EPB 1024   // edges per block in count/fill (256 threads x 4)

// ---------------------------------------------------------------------------
// Fused 2-layer MLP: H = tanh(X@W1 + b1) @ W2 + b2, all fp32 (no fp32 MFMA on
// CDNA4 -> vector ALU). Block: 64 rows x 128 cols, 256 threads, thread tile
// 8 rows x 4 cols (float4). Tanh intermediate kept in LDS (Ts).
// LDS = 8+16+32 = 56 KB -> 2 blocks/CU.
// ---------------------------------------------------------------------------
__global__ __launch_bounds__(256) void mlp_fused(
    const float* __restrict__ X, const float* __restrict__ W1,
    const float* __restrict__ b1, const float* __restrict__ W2,
    const float* __restrict__ b2, float* __restrict__ H, int nrows)
{
    __shared__ float As[TM][32];        // 8 KB
    __shared__ float Ws[32][IN_DIM];    // 16 KB
    __shared__ float Ts[TM][IN_DIM];    // 32 KB
    const int t   = threadIdx.x;
    const int tx  = t & 31;
    const int ty  = t >> 5;
    const int c0  = tx * 4;
    const int row0 = blockIdx.x * TM;

    float acc[8][4];
#pragma unroll
    for (int i = 0; i < 8; ++i)
        acc[i][0] = acc[i][1] = acc[i][2] = acc[i][3] = 0.f;

    // ---- phase 1: T = tanh(X @ W1 + b1) ----
    for (int kk = 0; kk < 4; ++kk) {
        __syncthreads();
#pragma unroll
        for (int s = 0; s < 2; ++s) {
            int idx = t + s * 256;
            int r = idx >> 3, q = idx & 7;
            int gr = row0 + r; gr = gr < nrows ? gr : nrows - 1;
            *(float4*)&As[r][q * 4] =
                *(const float4*)&X[(size_t)gr * IN_DIM + kk * 32 + q * 4];
        }
#pragma unroll
        for (int s = 0; s < 4; ++s) {
            int idx = t + s * 256;
            int r = idx >> 5, q = idx & 31;
            *(float4*)&Ws[r][q * 4] =
                *(const float4*)&W1[(size_t)(kk * 32 + r) * IN_DIM + q * 4];
        }
        __syncthreads();
#pragma unroll
        for (int k = 0; k < 32; ++k) {
            float4 w = *(const float4*)&Ws[k][c0];
#pragma unroll
            for (int i = 0; i < 8; ++i) {
                float a = As[ty * 8 + i][k];
                acc[i][0] += a * w.x; acc[i][1] += a * w.y;
                acc[i][2] += a * w.z; acc[i][3] += a * w.w;
            }
        }
    }
    {
        float4 bb = *(const float4*)&b1[c0];
#pragma unroll
        for (int i = 0; i < 8; ++i) {
            int r = ty * 8 + i;
            Ts[r][c0 + 0] = tanhf(acc[i][0] + bb.x);
            Ts[r][c0 + 1] = tanhf(acc[i][1] + bb.y);
            Ts[r][c0 + 2] = tanhf(acc[i][2] + bb.z);
            Ts[r][c0 + 3] = tanhf(acc[i][3] + bb.w);
        }
    }

    // ---- phase 2: H = T @ W2 + b2 ----
    float acc2[8][4];
#pragma unroll
    for (int i = 0; i < 8; ++i)
        acc2[i][0] = acc2[i][1] = acc2[i][2] = acc2[i][3] = 0.f;

    for (int kk = 0; kk < 4; ++kk) {
        __syncthreads();
#pragma unroll
        for (int s = 0; s < 4; ++s) {
            int idx = t + s * 256;
            int r = idx >> 5, q = idx & 31;
            *(float4*)&Ws[r][q * 4] =
                *(const float4*)&W2[(size_t)(kk * 32 + r) * IN_DIM + q * 4];
        }
        __syncthreads();
#pragma unroll
        for (int k = 0; k < 32; ++k) {
            float4 w = *(const float4*)&Ws[k][c0];
#pragma unroll
            for (int i = 0; i < 8; ++i) {
                float a = Ts[ty * 8 + i][kk * 32 + k];
                acc2[i][0] += a * w.x; acc2[i][1] += a * w.y;
                acc2[i][2] += a * w.z; acc2[i][3] += a * w.w;
            }
        }
    }
    {
        float4 bb = *(const float4*)&b2[c0];
#pragma unroll
        for (int i = 0; i < 8; ++i) {
            int r = row0 + ty * 8 + i;
            if (r < nrows) {
                float4 o = make_float4(acc2[i][0] + bb.x, acc2[i][1] + bb.y,
                                       acc2[i][2] + bb.z, acc2[i][3] + bb.w);
                *(float4*)&H[(size_t)r * IN_DIM + c0] = o;
            }
        }
    }
}

__global__ void build_flag(const int* __restrict__ node_idx,
                           int* __restrict__ flag, int B)
{
    int i = blockIdx.x * blockDim.x + threadIdx.x;
    if (i < B) flag[node_idx[i]] = 1;
}

// ---------------------------------------------------------------------------
// Contention-free edge compaction, 3 phases. Active edge: flag[src] set and
// (src!=dst || selfw!=0), selfw = mask[ind] in {0,1}.
// Phase 1: per-block active count (+ rowsum atomics, ~16-way/addr, fine).
// ---------------------------------------------------------------------------
__global__ __launch_bounds__(256) void edge_count(
    const int* __restrict__ edges, const int* __restrict__ flag,
    const int* __restrict__ indp, float* __restrict__ rowsum,
    int* __restrict__ bcount, int E)
{
    const int t  = threadIdx.x;
    const int e0 = blockIdx.x * EPB;
    const float selfw = (*indp < 2) ? 1.0f : 0.0f;
    int cnt = 0;
#pragma unroll
    for (int j = 0; j < 4; ++j) {
        int e = e0 + j * 256 + t;
        if (e < E) {
            int2 ed = ((const int2*)edges)[e];
            bool act = (flag[ed.x] != 0) && (ed.x != ed.y || selfw != 0.0f);
            if (act) { ++cnt; atomicAdd(&rowsum[ed.x], 1.0f); }
        }
    }
    // block reduce
#pragma unroll
    for (int off = 32; off > 0; off >>= 1) cnt += __shfl_down(cnt, off, 64);
    __shared__ int wsum[4];
    if ((t & 63) == 0) wsum[t >> 6] = cnt;
    __syncthreads();
    if (t == 0) bcount[blockIdx.x] = wsum[0] + wsum[1] + wsum[2] + wsum[3];
}

// Phase 2: exclusive scan of block counts (one 1024-thread block; nb <= 1024).
__global__ __launch_bounds__(1024) void scan_blocks(
    const int* __restrict__ bcount, int* __restrict__ bbase,
    int* __restrict__ counter, int nb)
{
    __shared__ int sc[1024];
    int t = threadIdx.x;
    int v = (t < nb) ? bcount[t] : 0;
    sc[t] = v;
    __syncthreads();
#pragma unroll
    for (int off = 1; off < 1024; off <<= 1) {
        int u = 0;
        if (t >= off) u = sc[t - off];
        __syncthreads();
        if (t >= off) sc[t] += u;
        __syncthreads();
    }
    if (t < nb) bbase[t] = sc[t] - v;          // exclusive
    if (t == 1023) *counter = sc[1023];        // total active edges
}

// Phase 3: write compacted edges at bbase[blk] + intra-block rank.
__global__ __launch_bounds__(256) void edge_fill(
    const int* __restrict__ edges, const int* __restrict__ flag,
    const int* __restrict__ indp, const int* __restrict__ bbase,
    unsigned int* __restrict__ elist, int E)
{
    const int t  = threadIdx.x;
    const int e0 = blockIdx.x * EPB;
    const float selfw = (*indp < 2) ? 1.0f : 0.0f;
    unsigned int pack[4];
    int cnt = 0;
#pragma unroll
    for (int j = 0; j < 4; ++j) {
        int e = e0 + j * 256 + t;
        if (e < E) {
            int2 ed = ((const int2*)edges)[e];
            bool act = (flag[ed.x] != 0) && (ed.x != ed.y || selfw != 0.0f);
            if (act) pack[cnt++] = ((unsigned)ed.x << 16) | (unsigned)ed.y;
        }
    }
    // block-wide exclusive scan of per-thread counts
    __shared__ int sc[256];
    sc[t] = cnt;
    __syncthreads();
#pragma unroll
    for (int off = 1; off < 256; off <<= 1) {
        int u = 0;
        if (t >= off) u = sc[t - off];
        __syncthreads();
        if (t >= off) sc[t] += u;
        __syncthreads();
    }
    int base = bbase[blockIdx.x] + sc[t] - cnt;
    for (int i = 0; i < cnt; ++i) elist[base + i] = pack[i];
}

// ---------------------------------------------------------------------------
// One wave per compacted edge: acc[s] += h[d] (128 floats, 2/lane, fp32
// atomics). Gathers of h hit L2/L3 (h = 25.6 MB).
// ---------------------------------------------------------------------------
__global__ void aggregate(const unsigned int* __restrict__ elist,
                          const int* __restrict__ counter,
                          const float* __restrict__ H,
                          float* __restrict__ acc)
{
    int nE   = *counter;
    int lane = threadIdx.x & 63;
    int wid  = (int)((blockIdx.x * blockDim.x + threadIdx.x) >> 6);
    int nw   = (int)((gridDim.x * blockDim.x) >> 6);
    for (int e = wid; e < nE; e += nw) {
        unsigned int p = elist[e];
        int s = (int)(p >> 16), d = (int)(p & 0xFFFFu);
        float2 hv = *(const float2*)&H[(size_t)d * 128 + lane * 2];
        atomicAdd(&acc[(size_t)s * 128 + lane * 2 + 0], hv.x);
        atomicAdd(&acc[(size_t)s * 128 + lane * 2 + 1], hv.y);
    }
}

__global__ void gather_out(const int* __restrict__ node_idx,
                           const float* __restrict__ acc,
                           const float* __restrict__ rowsum,
                           float* __restrict__ out, int B)
{
    int i = blockIdx.x * blockDim.x + threadIdx.x;
    if (i >= B * 32) return;
    int b = i >> 5, q = i & 31;
    int v = node_idx[b];
    float rs = rowsum[v];
    float inv = (rs == 0.0f) ? 1.0f : 1.0f / rs;
    float4 a = ((const float4*)acc)[(size_t)v * 32 + q];
    ((float4*)out)[i] = make_float4(a.x * inv, a.y * inv, a.z * inv, a.w * inv);
}

extern "C" void kernel_launch(void* const* d_in, const int* in_sizes, int n_in,
                              void* d_out, int out_size, void* d_ws, size_t ws_size,
                              hipStream_t stream)
{
    const int*   edges    = (const int*)d_in[0];
    const int*   node_idx = (const int*)d_in[1];
    const float* X        = (const float*)d_in[2];
    const float* W1       = (const float*)d_in[3];
    const float* b1       = (const float*)d_in[4];
    const float* W2       = (const float*)d_in[5];
    const float* b2       = (const float*)d_in[6];
    const int*   indp     = (const int*)d_in[7];

    const int E = in_sizes[0] / 2;
    const int B = in_sizes[1];
    const int N = in_sizes[2] / IN_DIM;
    const int nb = (E + EPB - 1) / EPB;   // 782 for E=800000 (<=1024 required)

    // workspace layout (16B aligned for N=50000):
    // [acc N*128][rowsum N][flag N][counter 16B][H N*128][elist E][bcount nb][bbase nb]
    char*  ws      = (char*)d_ws;
    float* acc     = (float*)ws;
    float* rowsum  = (float*)(ws + (size_t)N * 128 * 4);
    int*   flag    = (int*)  (ws + (size_t)N * 129 * 4);
    int*   counter = (int*)  (ws + (size_t)N * 130 * 4);
    float* H       = (float*)(ws + (size_t)N * 130 * 4 + 16);
    unsigned int* elist =
        (unsigned int*)(ws + (size_t)N * 130 * 4 + 16 + (size_t)N * 128 * 4);
    int* bcount = (int*)((char*)elist + (size_t)E * 4);
    int* bbase  = bcount + nb;

    // zero acc + rowsum + flag + counter (acc must start at 0; rest logical 0)
    size_t zbytes = (size_t)N * 130 * 4 + 16;
    hipMemsetAsync(d_ws, 0, zbytes, stream);

    hipLaunchKernelGGL(build_flag, dim3((B + 255) / 256), dim3(256), 0, stream,
                       node_idx, flag, B);
    hipLaunchKernelGGL(mlp_fused, dim3((N + TM - 1) / TM), dim3(256), 0, stream,
                       X, W1, b1, W2, b2, H, N);
    hipLaunchKernelGGL(edge_count, dim3(nb), dim3(256), 0, stream,
                       edges, flag, indp, rowsum, bcount, E);
    hipLaunchKernelGGL(scan_blocks, dim3(1), dim3(1024), 0, stream,
                       bcount, bbase, counter, nb);
    hipLaunchKernelGGL(edge_fill, dim3(nb), dim3(256), 0, stream,
                       edges, flag, indp, bbase, elist, E);
    hipLaunchKernelGGL(aggregate, dim3(2048), dim3(256), 0, stream,
                       elist, counter, H, acc);
    hipLaunchKernelGGL(gather_out, dim3((B * 32 + 255) / 256), dim3(256), 0,
                       stream, node_idx, acc, rowsum, (float*)d_out, B);
}

// Round 3
// 228.945 us; speedup vs baseline: 2.0255x; 1.4677x over previous
//
#include <hip/hip_runtime.h>

#define IN_DIM 128
#define TM 64
#define SCAN_CHUNK 1024   // elements per block in scan1 (256 threads x 4)

// ---------------------------------------------------------------------------
// Fused 2-layer MLP: H = tanh(X@W1 + b1) @ W2 + b2, all fp32 (no fp32 MFMA on
// CDNA4 -> vector ALU). Block: 64 rows x 128 cols, 256 threads, thread tile
// 8 rows x 4 cols (float4). Tanh intermediate kept in LDS (Ts).
// LDS = 8+16+32 = 56 KB -> 2 blocks/CU.
// ---------------------------------------------------------------------------
__global__ __launch_bounds__(256) void mlp_fused(
    const float* __restrict__ X, const float* __restrict__ W1,
    const float* __restrict__ b1, const float* __restrict__ W2,
    const float* __restrict__ b2, float* __restrict__ H, int nrows)
{
    __shared__ float As[TM][32];        // 8 KB
    __shared__ float Ws[32][IN_DIM];    // 16 KB
    __shared__ float Ts[TM][IN_DIM];    // 32 KB
    const int t   = threadIdx.x;
    const int tx  = t & 31;
    const int ty  = t >> 5;
    const int c0  = tx * 4;
    const int row0 = blockIdx.x * TM;

    float acc[8][4];
#pragma unroll
    for (int i = 0; i < 8; ++i)
        acc[i][0] = acc[i][1] = acc[i][2] = acc[i][3] = 0.f;

    // ---- phase 1: T = tanh(X @ W1 + b1) ----
    for (int kk = 0; kk < 4; ++kk) {
        __syncthreads();
#pragma unroll
        for (int s = 0; s < 2; ++s) {
            int idx = t + s * 256;
            int r = idx >> 3, q = idx & 7;
            int gr = row0 + r; gr = gr < nrows ? gr : nrows - 1;
            *(float4*)&As[r][q * 4] =
                *(const float4*)&X[(size_t)gr * IN_DIM + kk * 32 + q * 4];
        }
#pragma unroll
        for (int s = 0; s < 4; ++s) {
            int idx = t + s * 256;
            int r = idx >> 5, q = idx & 31;
            *(float4*)&Ws[r][q * 4] =
                *(const float4*)&W1[(size_t)(kk * 32 + r) * IN_DIM + q * 4];
        }
        __syncthreads();
#pragma unroll
        for (int k = 0; k < 32; ++k) {
            float4 w = *(const float4*)&Ws[k][c0];
#pragma unroll
            for (int i = 0; i < 8; ++i) {
                float a = As[ty * 8 + i][k];
                acc[i][0] += a * w.x; acc[i][1] += a * w.y;
                acc[i][2] += a * w.z; acc[i][3] += a * w.w;
            }
        }
    }
    {
        float4 bb = *(const float4*)&b1[c0];
#pragma unroll
        for (int i = 0; i < 8; ++i) {
            int r = ty * 8 + i;
            Ts[r][c0 + 0] = tanhf(acc[i][0] + bb.x);
            Ts[r][c0 + 1] = tanhf(acc[i][1] + bb.y);
            Ts[r][c0 + 2] = tanhf(acc[i][2] + bb.z);
            Ts[r][c0 + 3] = tanhf(acc[i][3] + bb.w);
        }
    }

    // ---- phase 2: H = T @ W2 + b2 ----
    float acc2[8][4];
#pragma unroll
    for (int i = 0; i < 8; ++i)
        acc2[i][0] = acc2[i][1] = acc2[i][2] = acc2[i][3] = 0.f;

    for (int kk = 0; kk < 4; ++kk) {
        __syncthreads();
#pragma unroll
        for (int s = 0; s < 4; ++s) {
            int idx = t + s * 256;
            int r = idx >> 5, q = idx & 31;
            *(float4*)&Ws[r][q * 4] =
                *(const float4*)&W2[(size_t)(kk * 32 + r) * IN_DIM + q * 4];
        }
        __syncthreads();
#pragma unroll
        for (int k = 0; k < 32; ++k) {
            float4 w = *(const float4*)&Ws[k][c0];
#pragma unroll
            for (int i = 0; i < 8; ++i) {
                float a = Ts[ty * 8 + i][kk * 32 + k];
                acc2[i][0] += a * w.x; acc2[i][1] += a * w.y;
                acc2[i][2] += a * w.z; acc2[i][3] += a * w.w;
            }
        }
    }
    {
        float4 bb = *(const float4*)&b2[c0];
#pragma unroll
        for (int i = 0; i < 8; ++i) {
            int r = row0 + ty * 8 + i;
            if (r < nrows) {
                float4 o = make_float4(acc2[i][0] + bb.x, acc2[i][1] + bb.y,
                                       acc2[i][2] + bb.z, acc2[i][3] + bb.w);
                *(float4*)&H[(size_t)r * IN_DIM + c0] = o;
            }
        }
    }
}

__global__ void build_flag(const int* __restrict__ node_idx,
                           int* __restrict__ flag, int B)
{
    int i = blockIdx.x * blockDim.x + threadIdx.x;
    if (i < B) flag[node_idx[i]] = 1;
}

// ---------------------------------------------------------------------------
// deg[src] = count of kept edges (flagged src, not a dropped self-loop).
// Note rowsum == deg exactly: all kept weights are 1.0, zero-weight self
// edges are excluded from BOTH numerator and denominator in the reference.
// ---------------------------------------------------------------------------
__global__ __launch_bounds__(256) void edge_count(
    const int* __restrict__ edges, const int* __restrict__ flag,
    const int* __restrict__ indp, int* __restrict__ deg, int E)
{
    const float selfw = (*indp < 2) ? 1.0f : 0.0f;
    int e = blockIdx.x * blockDim.x + threadIdx.x;
    if (e < E) {
        int2 ed = ((const int2*)edges)[e];
        if (flag[ed.x] != 0 && (ed.x != ed.y || selfw != 0.0f))
            atomicAdd(&deg[ed.x], 1);
    }
}

// ---- 3-step exclusive scan of deg[N] -> rowstart[N] (+ total) ----
__global__ __launch_bounds__(256) void scan1(
    const int* __restrict__ deg, int* __restrict__ rowstart,
    int* __restrict__ bsum, int N)
{
    int t = threadIdx.x;
    int base = blockIdx.x * SCAN_CHUNK;
    int v[4], s = 0;
#pragma unroll
    for (int j = 0; j < 4; ++j) {
        int i = base + t * 4 + j;
        v[j] = (i < N) ? deg[i] : 0;
        s += v[j];
    }
    __shared__ int sc[256];
    sc[t] = s;
    __syncthreads();
#pragma unroll
    for (int off = 1; off < 256; off <<= 1) {
        int u = 0;
        if (t >= off) u = sc[t - off];
        __syncthreads();
        if (t >= off) sc[t] += u;
        __syncthreads();
    }
    int run = sc[t] - s;   // exclusive prefix for this thread's 4 elems
#pragma unroll
    for (int j = 0; j < 4; ++j) {
        int i = base + t * 4 + j;
        if (i < N) rowstart[i] = run;
        run += v[j];
    }
    if (t == 255) bsum[blockIdx.x] = sc[255];
}

__global__ void scan2(const int* __restrict__ bsum, int* __restrict__ bbase,
                      int* __restrict__ rowstart, int nb, int N)
{
    // single thread: nb ~ 49, negligible
    if (threadIdx.x == 0 && blockIdx.x == 0) {
        int run = 0;
        for (int i = 0; i < nb; ++i) { bbase[i] = run; run += bsum[i]; }
        rowstart[N] = run;   // total kept edges
    }
}

__global__ __launch_bounds__(256) void scan3(
    int* __restrict__ rowstart, const int* __restrict__ bbase, int N)
{
    int i = blockIdx.x * blockDim.x + threadIdx.x;
    if (i < N) rowstart[i] += bbase[i >> 10];
}

// ---------------------------------------------------------------------------
// Scatter kept edges into CSR: col[rowstart[src] + cursor[src]++] = dst.
// Per-node atomic contention ~ deg ~ 16. dst < 65536 -> ushort.
// ---------------------------------------------------------------------------
__global__ __launch_bounds__(256) void edge_fill_csr(
    const int* __restrict__ edges, const int* __restrict__ flag,
    const int* __restrict__ indp, const int* __restrict__ rowstart,
    int* __restrict__ cursor, unsigned short* __restrict__ col, int E)
{
    const float selfw = (*indp < 2) ? 1.0f : 0.0f;
    int e = blockIdx.x * blockDim.x + threadIdx.x;
    if (e < E) {
        int2 ed = ((const int2*)edges)[e];
        if (flag[ed.x] != 0 && (ed.x != ed.y || selfw != 0.0f)) {
            int p = atomicAdd(&cursor[ed.x], 1);
            col[rowstart[ed.x] + p] = (unsigned short)ed.y;
        }
    }
}

// ---------------------------------------------------------------------------
// One wave per node: acc[v] = (sum over CSR edges of H[dst]) / max(deg,1).
// 2 floats/lane in registers, broadcast col read + coalesced 512B H gather
// (H is 25.6 MB -> L2/L3 resident). Non-atomic store, flagged nodes only.
// ---------------------------------------------------------------------------
__global__ __launch_bounds__(256) void aggregate_csr(
    const int* __restrict__ rowstart, const unsigned short* __restrict__ col,
    const int* __restrict__ flag, const float* __restrict__ H,
    float* __restrict__ acc, int N)
{
    int wid = (int)((blockIdx.x * blockDim.x + threadIdx.x) >> 6);
    if (wid >= N) return;
    if (flag[wid] == 0) return;
    int lane = threadIdx.x & 63;
    int s = rowstart[wid], e = rowstart[wid + 1];
    float ax = 0.f, ay = 0.f, bx = 0.f, by = 0.f;
    int i = s;
    for (; i + 1 < e; i += 2) {          // 2-way unroll for ILP
        int d0 = col[i], d1 = col[i + 1];
        float2 h0 = *(const float2*)&H[(size_t)d0 * 128 + lane * 2];
        float2 h1 = *(const float2*)&H[(size_t)d1 * 128 + lane * 2];
        ax += h0.x; ay += h0.y;
        bx += h1.x; by += h1.y;
    }
    if (i < e) {
        int d0 = col[i];
        float2 h0 = *(const float2*)&H[(size_t)d0 * 128 + lane * 2];
        ax += h0.x; ay += h0.y;
    }
    float den = (e > s) ? (float)(e - s) : 1.0f;
    *(float2*)&acc[(size_t)wid * 128 + lane * 2] =
        make_float2((ax + bx) / den, (ay + by) / den);
}

__global__ void gather_out(const int* __restrict__ node_idx,
                           const float* __restrict__ acc,
                           float* __restrict__ out, int B)
{
    int i = blockIdx.x * blockDim.x + threadIdx.x;
    if (i >= B * 32) return;
    int b = i >> 5, q = i & 31;
    int v = node_idx[b];
    ((float4*)out)[i] = ((const float4*)acc)[(size_t)v * 32 + q];
}

extern "C" void kernel_launch(void* const* d_in, const int* in_sizes, int n_in,
                              void* d_out, int out_size, void* d_ws, size_t ws_size,
                              hipStream_t stream)
{
    const int*   edges    = (const int*)d_in[0];
    const int*   node_idx = (const int*)d_in[1];
    const float* X        = (const float*)d_in[2];
    const float* W1       = (const float*)d_in[3];
    const float* b1       = (const float*)d_in[4];
    const float* W2       = (const float*)d_in[5];
    const float* b2       = (const float*)d_in[6];
    const int*   indp     = (const int*)d_in[7];

    const int E = in_sizes[0] / 2;
    const int B = in_sizes[1];
    const int N = in_sizes[2] / IN_DIM;
    const int nb = (N + SCAN_CHUNK - 1) / SCAN_CHUNK;   // 49 for N=50000

    // workspace layout (zeroed region first):
    // [flag N][deg N][cursor N][counter 16B] | [bsum nb][bbase nb pad16]
    // [rowstart N+1 pad16][acc N*128][H N*128][col E u16]
    char* ws = (char*)d_ws;
    size_t off = 0;
    int* flag   = (int*)(ws + off); off += (size_t)N * 4;
    int* deg    = (int*)(ws + off); off += (size_t)N * 4;
    int* cursor = (int*)(ws + off); off += (size_t)N * 4;
    off += 16;                                    // spare
    const size_t zbytes = off;                    // memset range
    int* bsum  = (int*)(ws + off); off += (size_t)nb * 4;
    int* bbase = (int*)(ws + off); off += (size_t)nb * 4;
    off = (off + 15) & ~(size_t)15;
    int* rowstart = (int*)(ws + off); off += (size_t)(N + 1) * 4;
    off = (off + 15) & ~(size_t)15;
    float* acc = (float*)(ws + off); off += (size_t)N * IN_DIM * 4;
    float* H   = (float*)(ws + off); off += (size_t)N * IN_DIM * 4;
    unsigned short* col = (unsigned short*)(ws + off);

    hipMemsetAsync(d_ws, 0, zbytes, stream);

    hipLaunchKernelGGL(build_flag, dim3((B + 255) / 256), dim3(256), 0, stream,
                       node_idx, flag, B);
    hipLaunchKernelGGL(mlp_fused, dim3((N + TM - 1) / TM), dim3(256), 0, stream,
                       X, W1, b1, W2, b2, H, N);
    hipLaunchKernelGGL(edge_count, dim3((E + 255) / 256), dim3(256), 0, stream,
                       edges, flag, indp, deg, E);
    hipLaunchKernelGGL(scan1, dim3(nb), dim3(256), 0, stream,
                       deg, rowstart, bsum, N);
    hipLaunchKernelGGL(scan2, dim3(1), dim3(64), 0, stream,
                       bsum, bbase, rowstart, nb, N);
    hipLaunchKernelGGL(scan3, dim3((N + 255) / 256), dim3(256), 0, stream,
                       rowstart, bbase, N);
    hipLaunchKernelGGL(edge_fill_csr, dim3((E + 255) / 256), dim3(256), 0,
                       stream, edges, flag, indp, rowstart, cursor, col, E);
    hipLaunchKernelGGL(aggregate_csr, dim3((N * 64 + 255) / 256), dim3(256), 0,
                       stream, rowstart, col, flag, H, acc, N);
    hipLaunchKernelGGL(gather_out, dim3((B * 32 + 255) / 256), dim3(256), 0,
                       stream, node_idx, acc, (float*)d_out, B);
}

// Round 4
// 176.080 us; speedup vs baseline: 2.6337x; 1.3002x over previous
//
#include <hip/hip_runtime.h>

#define IN_DIM 128
#define SCAN_CHUNK 1024   // elements per block in scan1 (256 threads x 4)
#define LDW 40            // padded W-chunk k-stride (bf16 elems): 32 + 8
#define LDT 136           // padded Ts k-stride (bf16 elems): 128 + 8

typedef short v8s __attribute__((ext_vector_type(8)));   // 8 bf16 (4 VGPRs)
typedef float v4f __attribute__((ext_vector_type(4)));   // MFMA acc

__device__ inline unsigned short f2bf(float f) {
    unsigned int u = __float_as_uint(f);
    u += 0x7FFFu + ((u >> 16) & 1u);          // round-to-nearest-even
    return (unsigned short)(u >> 16);
}
__device__ inline float bf2f(unsigned short h) {
    return __uint_as_float((unsigned int)h << 16);
}

// ---------------------------------------------------------------------------
// W1/W2 (128x128 fp32, k-major rows) -> transposed bf16 hi/lo: Wt[n][k].
// hi = bf16(w), lo = bf16(w - hi): split eliminates correlated W-rounding err.
// 32768 elems total -> grid 128 x 256.
// ---------------------------------------------------------------------------
__global__ __launch_bounds__(256) void convert_w(
    const float* __restrict__ W1, const float* __restrict__ W2,
    unsigned short* __restrict__ Wt1h, unsigned short* __restrict__ Wt1l,
    unsigned short* __restrict__ Wt2h, unsigned short* __restrict__ Wt2l)
{
    int i = blockIdx.x * 256 + threadIdx.x;
    int m = i >> 14, rem = i & 16383;
    int n = rem >> 7, k = rem & 127;
    float w = (m ? W2 : W1)[k * 128 + n];
    unsigned short hi = f2bf(w);
    unsigned short lo = f2bf(w - bf2f(hi));
    (m ? Wt2h : Wt1h)[n * 128 + k] = hi;
    (m ? Wt2l : Wt1l)[n * 128 + k] = lo;
}

// X fp32 -> bf16 (single rounding; error averages down in the edge mean).
__global__ __launch_bounds__(256) void convert_x(
    const float* __restrict__ X, unsigned short* __restrict__ Xb, int n4)
{
    int i = blockIdx.x * 256 + threadIdx.x;
    if (i < n4) {
        float4 v = ((const float4*)X)[i];
        ushort4 o;
        o.x = f2bf(v.x); o.y = f2bf(v.y); o.z = f2bf(v.z); o.w = f2bf(v.w);
        ((ushort4*)Xb)[i] = o;
    }
}

// ---------------------------------------------------------------------------
// MFMA MLP: H = tanh(X@W1+b1)@W2+b2. Block = 128 rows x 128 cols, 4 waves,
// wave w -> rows [w*32, w*32+32) (2 row-tiles of 16). Per k-chunk(32):
// A-frags straight from global (zero reuse), B-frags (W hi/lo) from LDS,
// 2 MFMAs (hi+lo) per 16x16 tile sharing one accumulator. Ts holds tanh
// intermediate in bf16 (A-layout: row-major, k-contig, +8 pad). LDS 54 KB
// -> 2 blocks/CU. Frag maps: A[m=lane&15][k=quad*8+j]; B[n=lane&15][k=...];
// C/D col=lane&15, row=quad*4+reg (m89/m91/m120-verified).
// ---------------------------------------------------------------------------
__global__ __launch_bounds__(256) void mlp_mfma(
    const unsigned short* __restrict__ Xb,
    const unsigned short* __restrict__ Wt1h, const unsigned short* __restrict__ Wt1l,
    const unsigned short* __restrict__ Wt2h, const unsigned short* __restrict__ Wt2l,
    const float* __restrict__ b1, const float* __restrict__ b2,
    float* __restrict__ H, int nrows)
{
    __shared__ unsigned short Wh[128 * LDW];   // 10 KB
    __shared__ unsigned short Wl[128 * LDW];   // 10 KB
    __shared__ unsigned short Ts[128 * LDT];   // 34 KB
    const int t    = threadIdx.x;
    const int w    = t >> 6;
    const int lane = t & 63;
    const int l15  = lane & 15;
    const int quad = lane >> 4;
    const int R0   = blockIdx.x * 128;
    const int wrow = w * 32;

    v4f acc[2][8];
#pragma unroll
    for (int rt = 0; rt < 2; ++rt)
#pragma unroll
        for (int ct = 0; ct < 8; ++ct)
            acc[rt][ct] = (v4f){0.f, 0.f, 0.f, 0.f};

    // ---- phase 1: T = tanh(X @ W1 + b1) ----
    for (int kk = 0; kk < 4; ++kk) {
        __syncthreads();
#pragma unroll
        for (int s = 0; s < 2; ++s) {           // stage W1 hi/lo chunk
            int u = t + s * 256;                // 0..511
            int n = u >> 2, q = u & 3;
            *(uint4*)&Wh[n * LDW + q * 8] =
                *(const uint4*)&Wt1h[n * 128 + kk * 32 + q * 8];
            *(uint4*)&Wl[n * LDW + q * 8] =
                *(const uint4*)&Wt1l[n * 128 + kk * 32 + q * 8];
        }
        __syncthreads();
        v8s a[2];
#pragma unroll
        for (int rt = 0; rt < 2; ++rt) {
            int grow = R0 + wrow + rt * 16 + l15;
            grow = grow < nrows ? grow : nrows - 1;
            a[rt] = *(const v8s*)&Xb[(size_t)grow * 128 + kk * 32 + quad * 8];
        }
#pragma unroll
        for (int ct = 0; ct < 8; ++ct) {
            v8s bh = *(const v8s*)&Wh[(ct * 16 + l15) * LDW + quad * 8];
            v8s bl = *(const v8s*)&Wl[(ct * 16 + l15) * LDW + quad * 8];
#pragma unroll
            for (int rt = 0; rt < 2; ++rt) {
                acc[rt][ct] = __builtin_amdgcn_mfma_f32_16x16x32_bf16(
                    a[rt], bh, acc[rt][ct], 0, 0, 0);
                acc[rt][ct] = __builtin_amdgcn_mfma_f32_16x16x32_bf16(
                    a[rt], bl, acc[rt][ct], 0, 0, 0);
            }
        }
    }
    // epilogue 1: tanh -> Ts (bf16)
#pragma unroll
    for (int ct = 0; ct < 8; ++ct) {
        float bias = b1[ct * 16 + l15];
#pragma unroll
        for (int rt = 0; rt < 2; ++rt) {
            int rb = wrow + rt * 16 + quad * 4;
#pragma unroll
            for (int r = 0; r < 4; ++r)
                Ts[(rb + r) * LDT + ct * 16 + l15] =
                    f2bf(tanhf(acc[rt][ct][r] + bias));
            acc[rt][ct] = (v4f){0.f, 0.f, 0.f, 0.f};
        }
    }

    // ---- phase 2: H = T @ W2 + b2 ----
    for (int kk = 0; kk < 4; ++kk) {
        __syncthreads();   // kk==0: guards Ts writes + W1-chunk reads done
#pragma unroll
        for (int s = 0; s < 2; ++s) {           // stage W2 hi/lo chunk
            int u = t + s * 256;
            int n = u >> 2, q = u & 3;
            *(uint4*)&Wh[n * LDW + q * 8] =
                *(const uint4*)&Wt2h[n * 128 + kk * 32 + q * 8];
            *(uint4*)&Wl[n * LDW + q * 8] =
                *(const uint4*)&Wt2l[n * 128 + kk * 32 + q * 8];
        }
        __syncthreads();
        v8s a[2];
#pragma unroll
        for (int rt = 0; rt < 2; ++rt)
            a[rt] = *(const v8s*)
                &Ts[(wrow + rt * 16 + l15) * LDT + kk * 32 + quad * 8];
#pragma unroll
        for (int ct = 0; ct < 8; ++ct) {
            v8s bh = *(const v8s*)&Wh[(ct * 16 + l15) * LDW + quad * 8];
            v8s bl = *(const v8s*)&Wl[(ct * 16 + l15) * LDW + quad * 8];
#pragma unroll
            for (int rt = 0; rt < 2; ++rt) {
                acc[rt][ct] = __builtin_amdgcn_mfma_f32_16x16x32_bf16(
                    a[rt], bh, acc[rt][ct], 0, 0, 0);
                acc[rt][ct] = __builtin_amdgcn_mfma_f32_16x16x32_bf16(
                    a[rt], bl, acc[rt][ct], 0, 0, 0);
            }
        }
    }
    // epilogue 2: H (fp32)
#pragma unroll
    for (int ct = 0; ct < 8; ++ct) {
        float bias = b2[ct * 16 + l15];
#pragma unroll
        for (int rt = 0; rt < 2; ++rt) {
#pragma unroll
            for (int r = 0; r < 4; ++r) {
                int grow = R0 + wrow + rt * 16 + quad * 4 + r;
                if (grow < nrows)
                    H[(size_t)grow * 128 + ct * 16 + l15] = acc[rt][ct][r] + bias;
            }
        }
    }
}

__global__ void build_flag(const int* __restrict__ node_idx,
                           int* __restrict__ flag, int B)
{
    int i = blockIdx.x * blockDim.x + threadIdx.x;
    if (i < B) flag[node_idx[i]] = 1;
}

// deg[src] = kept-edge count (== row_sum exactly: kept weights are 1.0).
__global__ __launch_bounds__(256) void edge_count(
    const int* __restrict__ edges, const int* __restrict__ flag,
    const int* __restrict__ indp, int* __restrict__ deg, int E)
{
    const float selfw = (*indp < 2) ? 1.0f : 0.0f;
    int e = blockIdx.x * blockDim.x + threadIdx.x;
    if (e < E) {
        int2 ed = ((const int2*)edges)[e];
        if (flag[ed.x] != 0 && (ed.x != ed.y || selfw != 0.0f))
            atomicAdd(&deg[ed.x], 1);
    }
}

// ---- 3-step exclusive scan of deg[N] -> rowstart[N] (+ total) ----
__global__ __launch_bounds__(256) void scan1(
    const int* __restrict__ deg, int* __restrict__ rowstart,
    int* __restrict__ bsum, int N)
{
    int t = threadIdx.x;
    int base = blockIdx.x * SCAN_CHUNK;
    int v[4], s = 0;
#pragma unroll
    for (int j = 0; j < 4; ++j) {
        int i = base + t * 4 + j;
        v[j] = (i < N) ? deg[i] : 0;
        s += v[j];
    }
    __shared__ int sc[256];
    sc[t] = s;
    __syncthreads();
#pragma unroll
    for (int off = 1; off < 256; off <<= 1) {
        int u = 0;
        if (t >= off) u = sc[t - off];
        __syncthreads();
        if (t >= off) sc[t] += u;
        __syncthreads();
    }
    int run = sc[t] - s;
#pragma unroll
    for (int j = 0; j < 4; ++j) {
        int i = base + t * 4 + j;
        if (i < N) rowstart[i] = run;
        run += v[j];
    }
    if (t == 255) bsum[blockIdx.x] = sc[255];
}

__global__ void scan2(const int* __restrict__ bsum, int* __restrict__ bbase,
                      int* __restrict__ rowstart, int nb, int N)
{
    if (threadIdx.x == 0 && blockIdx.x == 0) {
        int run = 0;
        for (int i = 0; i < nb; ++i) { bbase[i] = run; run += bsum[i]; }
        rowstart[N] = run;
    }
}

__global__ __launch_bounds__(256) void scan3(
    int* __restrict__ rowstart, const int* __restrict__ bbase, int N)
{
    int i = blockIdx.x * blockDim.x + threadIdx.x;
    if (i < N) rowstart[i] += bbase[i >> 10];
}

__global__ __launch_bounds__(256) void edge_fill_csr(
    const int* __restrict__ edges, const int* __restrict__ flag,
    const int* __restrict__ indp, const int* __restrict__ rowstart,
    int* __restrict__ cursor, unsigned short* __restrict__ col, int E)
{
    const float selfw = (*indp < 2) ? 1.0f : 0.0f;
    int e = blockIdx.x * blockDim.x + threadIdx.x;
    if (e < E) {
        int2 ed = ((const int2*)edges)[e];
        if (flag[ed.x] != 0 && (ed.x != ed.y || selfw != 0.0f)) {
            int p = atomicAdd(&cursor[ed.x], 1);
            col[rowstart[ed.x] + p] = (unsigned short)ed.y;
        }
    }
}

// One wave per node: acc[v] = (sum_{CSR} H[dst]) / max(deg,1), no atomics.
__global__ __launch_bounds__(256) void aggregate_csr(
    const int* __restrict__ rowstart, const unsigned short* __restrict__ col,
    const int* __restrict__ flag, const float* __restrict__ H,
    float* __restrict__ acc, int N)
{
    int wid = (int)((blockIdx.x * blockDim.x + threadIdx.x) >> 6);
    if (wid >= N) return;
    if (flag[wid] == 0) return;
    int lane = threadIdx.x & 63;
    int s = rowstart[wid], e = rowstart[wid + 1];
    float ax = 0.f, ay = 0.f, bx = 0.f, by = 0.f;
    int i = s;
    for (; i + 1 < e; i += 2) {
        int d0 = col[i], d1 = col[i + 1];
        float2 h0 = *(const float2*)&H[(size_t)d0 * 128 + lane * 2];
        float2 h1 = *(const float2*)&H[(size_t)d1 * 128 + lane * 2];
        ax += h0.x; ay += h0.y;
        bx += h1.x; by += h1.y;
    }
    if (i < e) {
        int d0 = col[i];
        float2 h0 = *(const float2*)&H[(size_t)d0 * 128 + lane * 2];
        ax += h0.x; ay += h0.y;
    }
    float den = (e > s) ? (float)(e - s) : 1.0f;
    *(float2*)&acc[(size_t)wid * 128 + lane * 2] =
        make_float2((ax + bx) / den, (ay + by) / den);
}

__global__ void gather_out(const int* __restrict__ node_idx,
                           const float* __restrict__ acc,
                           float* __restrict__ out, int B)
{
    int i = blockIdx.x * blockDim.x + threadIdx.x;
    if (i >= B * 32) return;
    int b = i >> 5, q = i & 31;
    int v = node_idx[b];
    ((float4*)out)[i] = ((const float4*)acc)[(size_t)v * 32 + q];
}

extern "C" void kernel_launch(void* const* d_in, const int* in_sizes, int n_in,
                              void* d_out, int out_size, void* d_ws, size_t ws_size,
                              hipStream_t stream)
{
    const int*   edges    = (const int*)d_in[0];
    const int*   node_idx = (const int*)d_in[1];
    const float* X        = (const float*)d_in[2];
    const float* W1       = (const float*)d_in[3];
    const float* b1       = (const float*)d_in[4];
    const float* W2       = (const float*)d_in[5];
    const float* b2       = (const float*)d_in[6];
    const int*   indp     = (const int*)d_in[7];

    const int E = in_sizes[0] / 2;
    const int B = in_sizes[1];
    const int N = in_sizes[2] / IN_DIM;
    const int nb = (N + SCAN_CHUNK - 1) / SCAN_CHUNK;   // 49

    // workspace layout:
    // [flag N][deg N][cursor N][16B] | [bsum nb][bbase nb] [rowstart N+1]
    // [acc N*128 f32][H N*128 f32][col E u16] [Xb N*128 bf16]
    // [Wt1h][Wt1l][Wt2h][Wt2l] (each 16384 bf16)
    char* ws = (char*)d_ws;
    size_t off = 0;
    int* flag   = (int*)(ws + off); off += (size_t)N * 4;
    int* deg    = (int*)(ws + off); off += (size_t)N * 4;
    int* cursor = (int*)(ws + off); off += (size_t)N * 4;
    off += 16;
    const size_t zbytes = off;
    int* bsum  = (int*)(ws + off); off += (size_t)nb * 4;
    int* bbase = (int*)(ws + off); off += (size_t)nb * 4;
    off = (off + 15) & ~(size_t)15;
    int* rowstart = (int*)(ws + off); off += (size_t)(N + 1) * 4;
    off = (off + 15) & ~(size_t)15;
    float* acc = (float*)(ws + off); off += (size_t)N * IN_DIM * 4;
    float* H   = (float*)(ws + off); off += (size_t)N * IN_DIM * 4;
    unsigned short* col = (unsigned short*)(ws + off);
    off += (size_t)E * 2;
    off = (off + 15) & ~(size_t)15;
    unsigned short* Xb = (unsigned short*)(ws + off); off += (size_t)N * IN_DIM * 2;
    unsigned short* Wt1h = (unsigned short*)(ws + off); off += 16384 * 2;
    unsigned short* Wt1l = (unsigned short*)(ws + off); off += 16384 * 2;
    unsigned short* Wt2h = (unsigned short*)(ws + off); off += 16384 * 2;
    unsigned short* Wt2l = (unsigned short*)(ws + off); off += 16384 * 2;

    hipMemsetAsync(d_ws, 0, zbytes, stream);

    hipLaunchKernelGGL(build_flag, dim3((B + 255) / 256), dim3(256), 0, stream,
                       node_idx, flag, B);
    hipLaunchKernelGGL(convert_w, dim3(128), dim3(256), 0, stream,
                       W1, W2, Wt1h, Wt1l, Wt2h, Wt2l);
    hipLaunchKernelGGL(convert_x, dim3((N * IN_DIM / 4 + 255) / 256), dim3(256),
                       0, stream, X, Xb, N * IN_DIM / 4);
    hipLaunchKernelGGL(mlp_mfma, dim3((N + 127) / 128), dim3(256), 0, stream,
                       Xb, Wt1h, Wt1l, Wt2h, Wt2l, b1, b2, H, N);
    hipLaunchKernelGGL(edge_count, dim3((E + 255) / 256), dim3(256), 0, stream,
                       edges, flag, indp, deg, E);
    hipLaunchKernelGGL(scan1, dim3(nb), dim3(256), 0, stream,
                       deg, rowstart, bsum, N);
    hipLaunchKernelGGL(scan2, dim3(1), dim3(64), 0, stream,
                       bsum, bbase, rowstart, nb, N);
    hipLaunchKernelGGL(scan3, dim3((N + 255) / 256), dim3(256), 0, stream,
                       rowstart, bbase, N);
    hipLaunchKernelGGL(edge_fill_csr, dim3((E + 255) / 256), dim3(256), 0,
                       stream, edges, flag, indp, rowstart, cursor, col, E);
    hipLaunchKernelGGL(aggregate_csr, dim3((N * 64 + 255) / 256), dim3(256), 0,
                       stream, rowstart, col, flag, H, acc, N);
    hipLaunchKernelGGL(gather_out, dim3((B * 32 + 255) / 256), dim3(256), 0,
                       stream, node_idx, acc, (float*)d_out, B);
}